// Round 12
// baseline (331.039 us; speedup 1.0000x reference)
//
#include <hip/hip_runtime.h>
#include <math.h>

#define H 2048

__device__ __forceinline__ float sigmoidf_(float v) {
    return 1.0f / (1.0f + expf(-v));
}

__device__ __forceinline__ float dot4(float4 a, float4 b) {
    return a.x * b.x + a.y * b.y + a.z * b.z + a.w * b.w;
}

// Async global->LDS DMA, 16B per lane per instruction (1KB per wave-issue).
// LDS dest must be wave-uniform (HW writes lds + lane*16); global src is
// per-lane. Destinations are LDS, not VGPRs -> no RA/copy hazard (round-9
// NaN root cause), no VGPR cost per outstanding load. Completion is counted
// by vmcnt and drained by __syncthreads() (m97 pattern).
__device__ __forceinline__ void stage16(const float* g, float* l) {
    __builtin_amdgcn_global_load_lds(
        (const __attribute__((address_space(1))) void*)g,
        (__attribute__((address_space(3))) void*)l, 16, 0, 0);
}

extern __shared__ float lds[];

// Layers 1,2 — one block per output element t. Phase 1: 4 waves issue 16
// back-to-back 1KB global_load_lds each, staging all 8 weight rows (64KB):
// 16KB/wave in flight, ~128KB/CU with 2 resident blocks. Phase 2 (after one
// barrier): wave w computes gate w's full 2048-dot from LDS; x/h quads read
// from global (same 16KB for every block -> L1/L2-hot). One scalar butterfly
// per wave, tiny static-LDS combine, tid0 tail.
__global__ __launch_bounds__(256)
void lstm_layer(const float* __restrict__ Wih, const float* __restrict__ Whh,
                const float* __restrict__ bih, const float* __restrict__ bhh,
                const float* __restrict__ xin,  // [H] prev-layer h
                const float* __restrict__ hin,  // [H]
                const float* __restrict__ cin,  // [H]
                float* __restrict__ hout, float* __restrict__ cout)
{
    const int t    = blockIdx.x;          // 0..2047
    const int tid  = threadIdx.x;
    const int w    = tid >> 6;            // wave id = gate id
    const int lane = tid & 63;

    // ---- stage 64 x 1KB units; unit u handled by wave u&3 ----
    // unit u: row r = u>>3 (0-3: Wih gates, 4-7: Whh gates), quarter q = u&7
#pragma unroll
    for (int j = 0; j < 16; ++j) {
        const int u = (j << 2) | w;       // wave-uniform
        const int r = u >> 3, q = u & 7;
        const float* row = (r < 4) ? (Wih + (size_t)(r * H + t) * H)
                                   : (Whh + (size_t)((r - 4) * H + t) * H);
        stage16(row + q * 256 + lane * 4, lds + u * 256);
    }

    // per-wave gate bias (overlaps staging; w uniform per wave)
    const float bias = bih[w * H + t] + bhh[w * H + t];

    __syncthreads();   // drains vmcnt(0): all 64KB staged; barrier

    // ---- gate w: dot(Wih_row_w, x) + dot(Whh_row_w, h), from LDS ----
    const float4* wiq = (const float4*)lds + (size_t)w * 512;
    const float4* whq = (const float4*)lds + (size_t)(4 + w) * 512;
    const float4* xq  = (const float4*)xin;
    const float4* hq  = (const float4*)hin;
    float a0 = 0.0f, a1 = 0.0f;
#pragma unroll
    for (int j = 0; j < 8; ++j) {
        const int i = lane + 64 * j;
        a0 += dot4(wiq[i], xq[i]);        // LDS: consecutive lanes, 16B apart
        a1 += dot4(whq[i], hq[i]);        // -> conflict-free ds_read_b128
    }
    float s = a0 + a1;
#pragma unroll
    for (int off = 32; off > 0; off >>= 1) s += __shfl_down(s, off, 64);

    __shared__ float gates[4];
    if (lane == 0) gates[w] = s + bias;
    __syncthreads();
    if (tid == 0) {
        const float gi = gates[0], gf = gates[1], gg = gates[2], go = gates[3];
        const float cprev = cin[t];
        const float c2 = sigmoidf_(gf) * cprev + sigmoidf_(gi) * tanhf(gg);
        const float h2 = sigmoidf_(go) * tanhf(c2);
        cout[t] = c2;
        hout[t] = h2;
    }
}

// Layer 0 — Wih0 is [4H,1]: x*Wih0 folded into the bias. Stages only the 4
// Whh rows (32KB LDS -> ~5 blocks/CU); h read from global (L1-hot).
__global__ __launch_bounds__(256)
void lstm_layer0(const float* __restrict__ Wih0,  // [4H]
                 const float* __restrict__ Whh,   // [4H,H]
                 const float* __restrict__ bih, const float* __restrict__ bhh,
                 const float* __restrict__ xs,    // [1]
                 const float* __restrict__ hin, const float* __restrict__ cin,
                 float* __restrict__ hout, float* __restrict__ cout)
{
    const int t    = blockIdx.x;
    const int tid  = threadIdx.x;
    const int w    = tid >> 6;
    const int lane = tid & 63;

#pragma unroll
    for (int j = 0; j < 8; ++j) {
        const int u = (j << 2) | w;       // 0..31, wave-uniform
        const int r = u >> 3, q = u & 7;
        stage16(Whh + (size_t)(r * H + t) * H + q * 256 + lane * 4,
                lds + u * 256);
    }

    const float bias = bih[w * H + t] + bhh[w * H + t] + xs[0] * Wih0[w * H + t];

    __syncthreads();

    const float4* wq_ = (const float4*)lds + (size_t)w * 512;
    const float4* hq  = (const float4*)hin;
    float a0 = 0.0f, a1 = 0.0f;
#pragma unroll
    for (int j = 0; j < 8; j += 2) {
        const int i0 = lane + 64 * j, i1 = lane + 64 * (j + 1);
        a0 += dot4(wq_[i0], hq[i0]);
        a1 += dot4(wq_[i1], hq[i1]);
    }
    float s = a0 + a1;
#pragma unroll
    for (int off = 32; off > 0; off >>= 1) s += __shfl_down(s, off, 64);

    __shared__ float gates[4];
    if (lane == 0) gates[w] = s + bias;
    __syncthreads();
    if (tid == 0) {
        const float gi = gates[0], gf = gates[1], gg = gates[2], go = gates[3];
        const float cprev = cin[t];
        const float c2 = sigmoidf_(gf) * cprev + sigmoidf_(gi) * tanhf(gg);
        const float h2 = sigmoidf_(go) * tanhf(c2);
        cout[t] = c2;
        hout[t] = h2;
    }
}

// y = dot(Wout, h) + bout   (single block)
__global__ __launch_bounds__(256)
void out_proj(const float* __restrict__ Wout,
              const float* __restrict__ bout,
              const float* __restrict__ h,
              float* __restrict__ y)
{
    __shared__ float partl[4];
    const int tid = threadIdx.x;
    const float4* W4 = (const float4*)Wout;
    const float4* h4 = (const float4*)h;
    float acc = 0.0f;
#pragma unroll
    for (int k = 0; k < 2; ++k) {
        int i = tid + 256 * k;
        float4 a = W4[i];
        float4 b = h4[i];
        acc += a.x * b.x + a.y * b.y + a.z * b.z + a.w * b.w;
    }
#pragma unroll
    for (int off = 32; off > 0; off >>= 1) acc += __shfl_down(acc, off, 64);
    if ((tid & 63) == 0) partl[tid >> 6] = acc;
    __syncthreads();
    if (tid == 0) y[0] = partl[0] + partl[1] + partl[2] + partl[3] + bout[0];
}

extern "C" void kernel_launch(void* const* d_in, const int* in_sizes, int n_in,
                              void* d_out, int out_size, void* d_ws, size_t ws_size,
                              hipStream_t stream) {
    const float* x    = (const float*)d_in[0];
    const float* hin  = (const float*)d_in[1];   // [3,1,H]
    const float* cin  = (const float*)d_in[2];   // [3,1,H]
    const float* Wih0 = (const float*)d_in[3];
    const float* Whh0 = (const float*)d_in[4];
    const float* bih0 = (const float*)d_in[5];
    const float* bhh0 = (const float*)d_in[6];
    const float* Wih1 = (const float*)d_in[7];
    const float* Whh1 = (const float*)d_in[8];
    const float* bih1 = (const float*)d_in[9];
    const float* bhh1 = (const float*)d_in[10];
    const float* Wih2 = (const float*)d_in[11];
    const float* Whh2 = (const float*)d_in[12];
    const float* bih2 = (const float*)d_in[13];
    const float* bhh2 = (const float*)d_in[14];
    const float* Wout = (const float*)d_in[15];
    const float* bout = (const float*)d_in[16];

    float* out = (float*)d_out;
    float* y  = out;              // [1]
    float* hN = out + 1;          // [3,H]
    float* cN = out + 1 + 3 * H;  // [3,H]

    lstm_layer0<<<2048, 256, 32768, stream>>>(Wih0, Whh0, bih0, bhh0, x,
                                              hin, cin, hN, cN);
    lstm_layer<<<2048, 256, 65536, stream>>>(Wih1, Whh1, bih1, bhh1,
                                             hN, hin + H, cin + H,
                                             hN + H, cN + H);
    lstm_layer<<<2048, 256, 65536, stream>>>(Wih2, Whh2, bih2, bhh2,
                                             hN + H, hin + 2 * H, cin + 2 * H,
                                             hN + 2 * H, cN + 2 * H);
    out_proj<<<1, 256, 0, stream>>>(Wout, bout, hN + 2 * H, y);
}